// Round 1
// baseline (1217.784 us; speedup 1.0000x reference)
//
#include <hip/hip_runtime.h>

#define SEQ    512
#define NH     16
#define DH     64
#define DMODEL 1024
#define NB     16            // batch
#define MROWS  (NB*SEQ)      // 8192
#define KDIM   1024
#define MAXL   512

// ---------------------------------------------------------------------------
// GEMM: C(8192 x N) = A(8192 x 1024) @ B(1024 x N) + bias
// 128x128 tile, BK=8, 256 threads, 8x8 micro-tile.
// Micro-tile cols split as {tx*4..+3} and {64+tx*4..+3} so LDS B reads are
// 2-way (free) instead of 4-way bank conflicts.
// MODE 0: scatter into q/k/v head-major [b][h][n][d] buffers (QKV proj)
// MODE 1: plain row-major C write (output proj)
// ---------------------------------------------------------------------------
template<int MODE>
__global__ __launch_bounds__(256)
void gemm128(const float* __restrict__ A, const float* __restrict__ B,
             const float* __restrict__ bias, int N,
             float* __restrict__ C,
             float* __restrict__ qb, float* __restrict__ kb, float* __restrict__ vb)
{
    __shared__ float As[8][128];   // [k][row]
    __shared__ float Bs[8][128];   // [k][col]
    const int t  = threadIdx.x;
    const int tx = t & 15, ty = t >> 4;
    const int m0 = blockIdx.y * 128;
    const int n0 = blockIdx.x * 128;

    float acc[8][8];
    {
        float4 b0 = *(const float4*)(bias + n0 + tx * 4);
        float4 b1 = *(const float4*)(bias + n0 + 64 + tx * 4);
        #pragma unroll
        for (int i = 0; i < 8; ++i) {
            acc[i][0] = b0.x; acc[i][1] = b0.y; acc[i][2] = b0.z; acc[i][3] = b0.w;
            acc[i][4] = b1.x; acc[i][5] = b1.y; acc[i][6] = b1.z; acc[i][7] = b1.w;
        }
    }

    const int ar = t >> 1, akq = t & 1;    // A stage: row t/2, 4-float chunk t&1
    const int bk = t >> 5, bc = t & 31;    // B stage: k-row t/32, float4 col t&31
    const float* Ap = A + (size_t)(m0 + ar) * KDIM + akq * 4;
    const float* Bp = B + (size_t)bk * N + n0 + bc * 4;

    for (int k0 = 0; k0 < KDIM; k0 += 8) {
        float4 av = *(const float4*)(Ap + k0);
        float4 bv = *(const float4*)(Bp + (size_t)k0 * N);
        __syncthreads();
        As[akq * 4 + 0][ar] = av.x;        // transposed store (k-major)
        As[akq * 4 + 1][ar] = av.y;
        As[akq * 4 + 2][ar] = av.z;
        As[akq * 4 + 3][ar] = av.w;
        *(float4*)&Bs[bk][bc * 4] = bv;
        __syncthreads();
        #pragma unroll
        for (int kk = 0; kk < 8; ++kk) {
            float4 a0 = *(float4*)&As[kk][ty * 8];
            float4 a1 = *(float4*)&As[kk][ty * 8 + 4];
            float4 b0 = *(float4*)&Bs[kk][tx * 4];
            float4 b1 = *(float4*)&Bs[kk][64 + tx * 4];
            float a[8]  = {a0.x, a0.y, a0.z, a0.w, a1.x, a1.y, a1.z, a1.w};
            float bb[8] = {b0.x, b0.y, b0.z, b0.w, b1.x, b1.y, b1.z, b1.w};
            #pragma unroll
            for (int i = 0; i < 8; ++i)
                #pragma unroll
                for (int j = 0; j < 8; ++j)
                    acc[i][j] = fmaf(a[i], bb[j], acc[i][j]);
        }
    }

    if (MODE == 0) {
        // scatter to q/k/v [b][h][n][d]; each 4-col chunk stays inside one head
        #pragma unroll
        for (int i = 0; i < 8; ++i) {
            int r = m0 + ty * 8 + i;
            int bb_ = r >> 9, n = r & 511;
            #pragma unroll
            for (int g = 0; g < 2; ++g) {
                int c = n0 + g * 64 + tx * 4;
                int which = c >> 10, rem = c & 1023;
                int hh = rem >> 6, d = rem & 63;
                float* dst = (which == 0) ? qb : (which == 1) ? kb : vb;
                float4 v = make_float4(acc[i][g * 4 + 0], acc[i][g * 4 + 1],
                                       acc[i][g * 4 + 2], acc[i][g * 4 + 3]);
                *(float4*)(dst + ((size_t)(bb_ * NH + hh) * SEQ + n) * DH + d) = v;
            }
        }
    } else {
        #pragma unroll
        for (int i = 0; i < 8; ++i) {
            int r = m0 + ty * 8 + i;
            float4 v0 = make_float4(acc[i][0], acc[i][1], acc[i][2], acc[i][3]);
            float4 v1 = make_float4(acc[i][4], acc[i][5], acc[i][6], acc[i][7]);
            *(float4*)(C + (size_t)r * N + n0 + tx * 4) = v0;
            *(float4*)(C + (size_t)r * N + n0 + 64 + tx * 4) = v1;
        }
    }
}

// ---------------------------------------------------------------------------
// Flash-style attention with relative position bias.
// Block = one (b, h, 64-row Q tile); loops over 8 key tiles of 64.
// QK^T and PV phases are 4x4-micro register GEMMs over LDS tiles.
// Online softmax state (m, l) replicated across the 16 lanes sharing a row
// via __shfl_xor reductions (lanes with same ty are 16 consecutive lanes).
// LDS = exactly 64 KB -> 2 blocks/CU. All hot-loop LDS reads broadcast/2-way.
// ---------------------------------------------------------------------------
__global__ __launch_bounds__(256)
void attn_kernel(const float* __restrict__ qb, const float* __restrict__ kb,
                 const float* __restrict__ vb, const float* __restrict__ rel,
                 float* __restrict__ ob)
{
    __shared__ float Qt[64][64];   // [d][row]   (transposed)
    __shared__ float Kt[64][64];   // [d][key]   (transposed)
    __shared__ float Vs[64][64];   // [key][d]
    __shared__ float Ps[64][64];   // [key][row] (transposed P)

    const int t  = threadIdx.x;
    const int tx = t & 15, ty = t >> 4;
    const int bid = blockIdx.x;
    const int qt = bid & 7, bh = bid >> 3;
    const int h = bh & 15, b = bh >> 4;
    const float* qh = qb + ((size_t)bh * SEQ + qt * 64) * DH;
    const float* kh = kb + (size_t)bh * SEQ * DH;
    const float* vh = vb + (size_t)bh * SEQ * DH;

    // stage Q tile transposed (once per block)
    #pragma unroll
    for (int u = 0; u < 4; ++u) {
        int i4 = t + 256 * u;
        int row = i4 >> 4, d4 = i4 & 15;
        float4 v = *(const float4*)(qh + row * DH + d4 * 4);
        Qt[d4 * 4 + 0][row] = v.x;
        Qt[d4 * 4 + 1][row] = v.y;
        Qt[d4 * 4 + 2][row] = v.z;
        Qt[d4 * 4 + 3][row] = v.w;
    }

    float m[4], l[4], o[4][4];
    #pragma unroll
    for (int i = 0; i < 4; ++i) {
        m[i] = -1e30f; l[i] = 0.f;
        #pragma unroll
        for (int j = 0; j < 4; ++j) o[i][j] = 0.f;
    }

    const int i0 = qt * 64 + ty * 4;   // absolute query row base for this thread

    for (int kt = 0; kt < 8; ++kt) {
        __syncthreads();   // previous iter's PV reads done before restaging
        #pragma unroll
        for (int u = 0; u < 4; ++u) {
            int i4 = t + 256 * u;
            int row = i4 >> 4, d4 = i4 & 15;
            float4 kv = *(const float4*)(kh + (kt * 64 + row) * DH + d4 * 4);
            Kt[d4 * 4 + 0][row] = kv.x;
            Kt[d4 * 4 + 1][row] = kv.y;
            Kt[d4 * 4 + 2][row] = kv.z;
            Kt[d4 * 4 + 3][row] = kv.w;
            float4 vv = *(const float4*)(vh + (kt * 64 + row) * DH + d4 * 4);
            *(float4*)&Vs[row][d4 * 4] = vv;
        }
        __syncthreads();

        // ---- QK^T: s[4 rows][4 keys] ----
        float s[4][4];
        #pragma unroll
        for (int i = 0; i < 4; ++i)
            #pragma unroll
            for (int j = 0; j < 4; ++j) s[i][j] = 0.f;

        #pragma unroll 16
        for (int d = 0; d < 64; ++d) {
            float4 q4 = *(float4*)&Qt[d][ty * 4];
            float4 k4 = *(float4*)&Kt[d][tx * 4];
            float qa[4] = {q4.x, q4.y, q4.z, q4.w};
            float ka[4] = {k4.x, k4.y, k4.z, k4.w};
            #pragma unroll
            for (int i = 0; i < 4; ++i)
                #pragma unroll
                for (int j = 0; j < 4; ++j)
                    s[i][j] = fmaf(qa[i], ka[j], s[i][j]);
        }

        // ---- scale + rel-pos bias + online softmax ----
        const int j0 = kt * 64 + tx * 4;
        float pr[4][4];
        #pragma unroll
        for (int i = 0; i < 4; ++i) {
            float mt = -1e30f;
            #pragma unroll
            for (int j = 0; j < 4; ++j) {
                s[i][j] = s[i][j] * 0.125f
                        + rel[(size_t)(i0 + i - j0 - j + (MAXL - 1)) * NH + h];
                mt = fmaxf(mt, s[i][j]);
            }
            #pragma unroll
            for (int msk = 1; msk < 16; msk <<= 1)
                mt = fmaxf(mt, __shfl_xor(mt, msk, 64));
            float mn = fmaxf(m[i], mt);
            float al = __expf(m[i] - mn);
            m[i] = mn;
            float rs = 0.f;
            #pragma unroll
            for (int j = 0; j < 4; ++j) { pr[i][j] = __expf(s[i][j] - mn); rs += pr[i][j]; }
            #pragma unroll
            for (int msk = 1; msk < 16; msk <<= 1)
                rs += __shfl_xor(rs, msk, 64);
            l[i] = l[i] * al + rs;
            #pragma unroll
            for (int j = 0; j < 4; ++j) o[i][j] *= al;
        }

        // ---- stage P transposed: Ps[key][row] ----
        #pragma unroll
        for (int j = 0; j < 4; ++j) {
            *(float4*)&Ps[tx * 4 + j][ty * 4] =
                make_float4(pr[0][j], pr[1][j], pr[2][j], pr[3][j]);
        }
        __syncthreads();

        // ---- PV: o[4 rows][4 dims] ----
        #pragma unroll 16
        for (int j = 0; j < 64; ++j) {
            float4 p4 = *(float4*)&Ps[j][ty * 4];
            float4 v4 = *(float4*)&Vs[j][tx * 4];
            float pa[4] = {p4.x, p4.y, p4.z, p4.w};
            float va[4] = {v4.x, v4.y, v4.z, v4.w};
            #pragma unroll
            for (int i = 0; i < 4; ++i)
                #pragma unroll
                for (int jd = 0; jd < 4; ++jd)
                    o[i][jd] = fmaf(pa[i], va[jd], o[i][jd]);
        }
    }

    // ---- finalize: /l, write attn output in (B, N, h*dh) layout ----
    #pragma unroll
    for (int i = 0; i < 4; ++i) {
        float inv = 1.0f / l[i];
        size_t r = (size_t)b * SEQ + i0 + i;
        *(float4*)(ob + r * DMODEL + h * DH + tx * 4) =
            make_float4(o[i][0] * inv, o[i][1] * inv, o[i][2] * inv, o[i][3] * inv);
    }
}

// ---------------------------------------------------------------------------
extern "C" void kernel_launch(void* const* d_in, const int* in_sizes, int n_in,
                              void* d_out, int out_size, void* d_ws, size_t ws_size,
                              hipStream_t stream)
{
    const float* x    = (const float*)d_in[0];
    const float* wqkv = (const float*)d_in[1];
    const float* bqkv = (const float*)d_in[2];
    const float* rel  = (const float*)d_in[3];
    const float* wout = (const float*)d_in[4];
    const float* bout = (const float*)d_in[5];
    float* out = (float*)d_out;
    float* ws  = (float*)d_ws;

    const size_t HS = (size_t)MROWS * DMODEL;   // 8 Mi floats per buffer
    float* qbuf = ws;
    float* kbuf = ws + HS;
    float* vbuf = ws + 2 * HS;
    float* abuf = ws + 3 * HS;   // total ws use: 4 * 33.5 MB = 134 MB

    // 1) QKV projection + head-major scatter
    gemm128<0><<<dim3(3 * DMODEL / 128, MROWS / 128), 256, 0, stream>>>(
        x, wqkv, bqkv, 3 * DMODEL, nullptr, qbuf, kbuf, vbuf);

    // 2) flash attention with relative position bias
    attn_kernel<<<dim3(NB * NH * (SEQ / 64)), 256, 0, stream>>>(
        qbuf, kbuf, vbuf, rel, abuf);

    // 3) output projection
    gemm128<1><<<dim3(DMODEL / 128, MROWS / 128), 256, 0, stream>>>(
        abuf, wout, bout, DMODEL, out, nullptr, nullptr, nullptr);
}

// Round 2
// 284.173 us; speedup vs baseline: 4.2854x; 4.2854x over previous
//
#include <hip/hip_runtime.h>

#define SEQ    512
#define NH     16
#define DH     64
#define DMODEL 1024
#define NB     16
#define MROWS  (NB*SEQ)      // 8192
#define MAXL   512

typedef _Float16 f16;
typedef f16  f16x8 __attribute__((ext_vector_type(8)));
typedef f16  f16x4 __attribute__((ext_vector_type(4)));
typedef float f32x4 __attribute__((ext_vector_type(4)));

// async global->LDS, 16B per lane; LDS dest = wave-uniform base + lane*16
__device__ static inline void gll16(const f16* g, f16* l) {
    __builtin_amdgcn_global_load_lds(
        (const __attribute__((address_space(1))) void*)(g),
        (__attribute__((address_space(3))) void*)(l), 16, 0, 0);
}

// ---------------------------------------------------------------------------
// elementwise fp32 -> fp16 convert (n multiple of 1024)
// ---------------------------------------------------------------------------
__global__ __launch_bounds__(256)
void cvt_f32_f16(const float* __restrict__ in, f16* __restrict__ out, int n)
{
    int i = (blockIdx.x * 256 + threadIdx.x) * 4;
    if (i < n) {
        float4 v = *(const float4*)(in + i);
        f16x4 h = { (f16)v.x, (f16)v.y, (f16)v.z, (f16)v.w };
        *(f16x4*)(out + i) = h;
    }
}

// ---------------------------------------------------------------------------
// transpose + convert: out[c][r] = (f16) in[r][c]; R,C multiples of 32
// block (32,8), grid (C/32, R/32)
// ---------------------------------------------------------------------------
__global__ __launch_bounds__(256)
void transpose_cvt(const float* __restrict__ in, f16* __restrict__ out, int R, int C)
{
    __shared__ float tile[32][33];
    int c0 = blockIdx.x * 32, r0 = blockIdx.y * 32;
    int tx = threadIdx.x, ty = threadIdx.y;
    #pragma unroll
    for (int i = 0; i < 4; ++i)
        tile[ty + i * 8][tx] = in[(size_t)(r0 + ty + i * 8) * C + c0 + tx];
    __syncthreads();
    #pragma unroll
    for (int i = 0; i < 4; ++i)
        out[(size_t)(c0 + ty + i * 8) * R + r0 + tx] = (f16)tile[tx][ty + i * 8];
}

// ---------------------------------------------------------------------------
// MFMA GEMM (m97 structure): C(M x N) = A(M x K) @ Bt(N x K)^T + bias
// 128x128 tile, BK=32, 256 threads (2x2 waves of 64x64), fp16 in, fp32 acc.
// MODE 0: scatter fp16 into q/k/v [b][h][n][d]   (QKV projection, N=3072)
// MODE 1: fp32 row-major C with bias              (output projection)
// ---------------------------------------------------------------------------
template<int MODE>
__global__ __launch_bounds__(256)
void gemm_mfma(const f16* __restrict__ A, const f16* __restrict__ Bt,
               const float* __restrict__ bias, int N, int K,
               float* __restrict__ Cout,
               f16* __restrict__ qb, f16* __restrict__ kb, f16* __restrict__ vb)
{
    __shared__ f16 As[128 * 32];
    __shared__ f16 Bs[128 * 32];
    const int t = threadIdx.x;
    const int lane = t & 63, w = t >> 6;
    const int quad = lane >> 4, l16 = lane & 15;
    const int m0 = blockIdx.y * 128, n0 = blockIdx.x * 128;
    const int wm = (w & 1) * 64, wn = (w >> 1) * 64;

    f32x4 acc[4][4];
    #pragma unroll
    for (int i = 0; i < 4; ++i)
        #pragma unroll
        for (int j = 0; j < 4; ++j)
            acc[i][j] = f32x4{0.f, 0.f, 0.f, 0.f};

    // staging: flat half idx = t*8 + r*2048 -> row = idx/32, col = idx%32
    const int srow = t >> 2, scol = (t & 3) * 8;
    const f16* agp = A  + (size_t)(m0 + srow) * K + scol;
    const f16* bgp = Bt + (size_t)(n0 + srow) * K + scol;
    f16* alds = As + w * 512;   // + r*2048
    f16* blds = Bs + w * 512;

    for (int k0 = 0; k0 < K; k0 += 32) {
        __syncthreads();
        gll16(agp + k0,              alds);
        gll16(agp + k0 + 64 * K,     alds + 2048);
        gll16(bgp + k0,              blds);
        gll16(bgp + k0 + 64 * K,     blds + 2048);
        __syncthreads();   // compiler drains vmcnt before barrier

        f16x8 af[4], bf[4];
        #pragma unroll
        for (int ms = 0; ms < 4; ++ms)
            af[ms] = *(const f16x8*)&As[(wm + ms * 16 + l16) * 32 + quad * 8];
        #pragma unroll
        for (int ns = 0; ns < 4; ++ns)
            bf[ns] = *(const f16x8*)&Bs[(wn + ns * 16 + l16) * 32 + quad * 8];
        #pragma unroll
        for (int ms = 0; ms < 4; ++ms)
            #pragma unroll
            for (int ns = 0; ns < 4; ++ns)
                acc[ms][ns] = __builtin_amdgcn_mfma_f32_16x16x32_f16(
                    af[ms], bf[ns], acc[ms][ns], 0, 0, 0);
    }

    // C/D layout: col = l16, row = quad*4 + reg
    if (MODE == 0) {
        #pragma unroll
        for (int ns = 0; ns < 4; ++ns) {
            int col = n0 + wn + ns * 16 + l16;
            float bv = bias[col];
            int which = col >> 10;
            int h = (col & 1023) >> 6, d = col & 63;
            f16* dst = (which == 0) ? qb : (which == 1) ? kb : vb;
            #pragma unroll
            for (int ms = 0; ms < 4; ++ms) {
                int rowb = m0 + wm + ms * 16 + quad * 4;
                #pragma unroll
                for (int reg = 0; reg < 4; ++reg) {
                    int row = rowb + reg;
                    int b = row >> 9, n = row & 511;
                    dst[((size_t)(b * NH + h) * SEQ + n) * DH + d] =
                        (f16)(acc[ms][ns][reg] + bv);
                }
            }
        }
    } else {
        #pragma unroll
        for (int ns = 0; ns < 4; ++ns) {
            int col = n0 + wn + ns * 16 + l16;
            float bv = bias[col];
            #pragma unroll
            for (int ms = 0; ms < 4; ++ms) {
                int rowb = m0 + wm + ms * 16 + quad * 4;
                #pragma unroll
                for (int reg = 0; reg < 4; ++reg)
                    Cout[(size_t)(rowb + reg) * N + col] = acc[ms][ns][reg] + bv;
            }
        }
    }
}

// ---------------------------------------------------------------------------
// MFMA flash attention with relative position bias.
// Block = (b, h, 64 q-rows); 4 waves x 16 q-rows. 8 key tiles of 64.
// QK^T: A=Q[q][d], B=K[key][d]; S in C-layout (col=key=l16, row=q=quad*4+reg).
// Online softmax per reg with 16-lane shuffle reductions.
// P -> wave-private LDS [q][key] (A-layout relayout), PV with B=Vt[d][key].
// ---------------------------------------------------------------------------
__global__ __launch_bounds__(256)
void attn_mfma(const f16* __restrict__ qb, const f16* __restrict__ kb,
               const f16* __restrict__ vb, const float* __restrict__ rel,
               f16* __restrict__ ob)
{
    __shared__ f16 Ks[64 * 72];       // [key][d] pad 72
    __shared__ f16 Vt[64 * 72];       // [d][key] pad 72
    __shared__ f16 Pw[4][16 * 72];    // wave-private [q][key] pad 72
    __shared__ float relh[1024];      // rel[:, h]

    const int t = threadIdx.x;
    const int lane = t & 63, w = t >> 6;
    const int quad = lane >> 4, l16 = lane & 15;
    const int bid = blockIdx.x;
    const int qt = bid & 7, bh = bid >> 3;
    const int h = bh & 15, b = bh >> 4;
    const f16* qh = qb + ((size_t)bh * SEQ + qt * 64) * DH;
    const f16* kh = kb + (size_t)bh * SEQ * DH;
    const f16* vh = vb + (size_t)bh * SEQ * DH;

    for (int i = t; i < 2 * MAXL - 1; i += 256) relh[i] = rel[i * NH + h];

    // Q fragments (A-layout): lane -> Q[w*16 + l16][quad*8 + j (+32)]
    f16x8 qf[2];
    {
        const f16* qrow = qh + (w * 16 + l16) * DH + quad * 8;
        qf[0] = *(const f16x8*)(qrow);
        qf[1] = *(const f16x8*)(qrow + 32);
    }

    f32x4 o[4];
    float mrow[4], lrow[4];
    #pragma unroll
    for (int r = 0; r < 4; ++r) {
        o[r] = f32x4{0.f, 0.f, 0.f, 0.f};
        mrow[r] = -1e30f; lrow[r] = 0.f;
    }

    const int sr = t >> 2, sc = (t & 3) * 16;   // staging: row, 16-half chunk

    for (int kt = 0; kt < 8; ++kt) {
        __syncthreads();
        // stage K tile [64][72]
        {
            const f16* src = kh + (kt * 64 + sr) * DH + sc;
            float4 v0 = *(const float4*)(src);
            float4 v1 = *(const float4*)(src + 8);
            *(float4*)&Ks[sr * 72 + sc] = v0;
            *(float4*)&Ks[sr * 72 + sc + 8] = v1;
        }
        // stage V transposed [d][key]
        {
            const f16* src = vh + (kt * 64 + sr) * DH + sc;
            f16 vtmp[16];
            *(float4*)(vtmp) = *(const float4*)(src);
            *(float4*)(vtmp + 8) = *(const float4*)(src + 8);
            #pragma unroll
            for (int i = 0; i < 16; ++i)
                Vt[(sc + i) * 72 + sr] = vtmp[i];
        }
        __syncthreads();

        // ---- S = Q K^T : 4 key subtiles of 16 ----
        f32x4 sfr[4];
        #pragma unroll
        for (int nt = 0; nt < 4; ++nt) {
            f16x8 b0 = *(const f16x8*)&Ks[(nt * 16 + l16) * 72 + quad * 8];
            f16x8 b1 = *(const f16x8*)&Ks[(nt * 16 + l16) * 72 + quad * 8 + 32];
            f32x4 c = f32x4{0.f, 0.f, 0.f, 0.f};
            c = __builtin_amdgcn_mfma_f32_16x16x32_f16(qf[0], b0, c, 0, 0, 0);
            c = __builtin_amdgcn_mfma_f32_16x16x32_f16(qf[1], b1, c, 0, 0, 0);
            sfr[nt] = c;
        }

        // ---- scale + bias + online softmax (rows = quad*4+reg) ----
        const int irow0 = qt * 64 + w * 16 + quad * 4;
        const int jcol0 = kt * 64 + l16;
        float p[4][4], al[4];
        #pragma unroll
        for (int reg = 0; reg < 4; ++reg) {
            float sv[4], mt = -1e30f;
            #pragma unroll
            for (int nt = 0; nt < 4; ++nt) {
                sv[nt] = sfr[nt][reg] * 0.125f
                       + relh[irow0 + reg - (jcol0 + nt * 16) + (MAXL - 1)];
                mt = fmaxf(mt, sv[nt]);
            }
            #pragma unroll
            for (int msk = 1; msk < 16; msk <<= 1)
                mt = fmaxf(mt, __shfl_xor(mt, msk, 64));
            float mn = fmaxf(mrow[reg], mt);
            al[reg] = __expf(mrow[reg] - mn);
            mrow[reg] = mn;
            float rs = 0.f;
            #pragma unroll
            for (int nt = 0; nt < 4; ++nt) {
                p[nt][reg] = __expf(sv[nt] - mn);
                rs += p[nt][reg];
            }
            #pragma unroll
            for (int msk = 1; msk < 16; msk <<= 1)
                rs += __shfl_xor(rs, msk, 64);
            lrow[reg] = lrow[reg] * al[reg] + rs;
        }
        #pragma unroll
        for (int dt = 0; dt < 4; ++dt)
            #pragma unroll
            for (int reg = 0; reg < 4; ++reg)
                o[dt][reg] *= al[reg];

        // ---- P -> LDS (relayout to A-operand), wave-private ----
        f16* pw = &Pw[w][0];
        #pragma unroll
        for (int nt = 0; nt < 4; ++nt)
            #pragma unroll
            for (int reg = 0; reg < 4; ++reg)
                pw[(quad * 4 + reg) * 72 + nt * 16 + l16] = (f16)p[nt][reg];
        __builtin_amdgcn_s_waitcnt(0xC07F);   // lgkmcnt(0): P visible to own wave

        // ---- O += P V ----
        #pragma unroll
        for (int s2 = 0; s2 < 2; ++s2) {
            f16x8 pa = *(const f16x8*)&pw[l16 * 72 + s2 * 32 + quad * 8];
            #pragma unroll
            for (int dt = 0; dt < 4; ++dt) {
                f16x8 vb8 = *(const f16x8*)&Vt[(dt * 16 + l16) * 72 + s2 * 32 + quad * 8];
                o[dt] = __builtin_amdgcn_mfma_f32_16x16x32_f16(pa, vb8, o[dt], 0, 0, 0);
            }
        }
    }

    // ---- finalize: /l, write fp16 attn-out in (B, N, h*dh) layout ----
    const int nbase = qt * 64 + w * 16 + quad * 4;
    #pragma unroll
    for (int reg = 0; reg < 4; ++reg) {
        float inv = 1.0f / lrow[reg];
        size_t rb = ((size_t)b * SEQ + nbase + reg) * DMODEL + h * DH;
        #pragma unroll
        for (int dt = 0; dt < 4; ++dt)
            ob[rb + dt * 16 + l16] = (f16)(o[dt][reg] * inv);
    }
}

// ---------------------------------------------------------------------------
extern "C" void kernel_launch(void* const* d_in, const int* in_sizes, int n_in,
                              void* d_out, int out_size, void* d_ws, size_t ws_size,
                              hipStream_t stream)
{
    const float* x    = (const float*)d_in[0];
    const float* wqkv = (const float*)d_in[1];
    const float* bqkv = (const float*)d_in[2];
    const float* rel  = (const float*)d_in[3];
    const float* wout = (const float*)d_in[4];
    const float* bout = (const float*)d_in[5];
    float* out = (float*)d_out;
    char* ws = (char*)d_ws;

    const size_t XH    = (size_t)MROWS * DMODEL;        // 8M elements
    f16* xh     = (f16*)(ws);                            // 16 MB
    f16* wqkvT  = (f16*)(ws + 2 * XH);                   // 6 MB (3072x1024)
    f16* woutT  = wqkvT + (size_t)3 * DMODEL * DMODEL;   // 2 MB (1024x1024)
    f16* qbuf   = woutT + (size_t)DMODEL * DMODEL;       // 16 MB each
    f16* kbuf   = qbuf + XH;
    f16* vbuf   = kbuf + XH;
    f16* abuf   = vbuf + XH;

    // converts
    cvt_f32_f16<<<XH / 1024, 256, 0, stream>>>(x, xh, (int)XH);
    transpose_cvt<<<dim3(3 * DMODEL / 32, DMODEL / 32), dim3(32, 8), 0, stream>>>(
        wqkv, wqkvT, DMODEL, 3 * DMODEL);
    transpose_cvt<<<dim3(DMODEL / 32, DMODEL / 32), dim3(32, 8), 0, stream>>>(
        wout, woutT, DMODEL, DMODEL);

    // 1) QKV projection (M=8192, N=3072, K=1024) + head-major fp16 scatter
    gemm_mfma<0><<<dim3(3 * DMODEL / 128, MROWS / 128), 256, 0, stream>>>(
        xh, wqkvT, bqkv, 3 * DMODEL, DMODEL, nullptr, qbuf, kbuf, vbuf);

    // 2) flash attention
    attn_mfma<<<dim3(NB * NH * (SEQ / 64)), 256, 0, stream>>>(
        qbuf, kbuf, vbuf, rel, abuf);

    // 3) output projection (M=8192, N=1024, K=1024), fp32 out + bias
    gemm_mfma<1><<<dim3(DMODEL / 128, MROWS / 128), 256, 0, stream>>>(
        abuf, woutT, bout, DMODEL, DMODEL, out, nullptr, nullptr, nullptr);
}

// Round 3
// 251.798 us; speedup vs baseline: 4.8364x; 1.1286x over previous
//
#include <hip/hip_runtime.h>

#define SEQ    512
#define NH     16
#define DH     64
#define DMODEL 1024
#define NB     16
#define MROWS  (NB*SEQ)      // 8192
#define MAXL   512

typedef _Float16 f16;
typedef f16  f16x8 __attribute__((ext_vector_type(8)));
typedef f16  f16x4 __attribute__((ext_vector_type(4)));
typedef float f32x4 __attribute__((ext_vector_type(4)));

// async global->LDS, 16B per lane; global addr is per-lane, LDS dest = wave-uniform base + lane*16
__device__ static inline void gll16(const f16* g, f16* l) {
    __builtin_amdgcn_global_load_lds(
        (const __attribute__((address_space(1))) void*)(g),
        (__attribute__((address_space(3))) void*)(l), 16, 0, 0);
}

// ---------------------------------------------------------------------------
// elementwise fp32 -> fp16 convert
// ---------------------------------------------------------------------------
__global__ __launch_bounds__(256)
void cvt_f32_f16(const float* __restrict__ in, f16* __restrict__ out, int n)
{
    int i = (blockIdx.x * 256 + threadIdx.x) * 4;
    if (i < n) {
        float4 v = *(const float4*)(in + i);
        f16x4 h = { (f16)v.x, (f16)v.y, (f16)v.z, (f16)v.w };
        *(f16x4*)(out + i) = h;
    }
}

// ---------------------------------------------------------------------------
// transpose + convert: out[c][r] = (f16) in[r][c]
// ---------------------------------------------------------------------------
__global__ __launch_bounds__(256)
void transpose_cvt(const float* __restrict__ in, f16* __restrict__ out, int R, int C)
{
    __shared__ float tile[32][33];
    int c0 = blockIdx.x * 32, r0 = blockIdx.y * 32;
    int tx = threadIdx.x, ty = threadIdx.y;
    #pragma unroll
    for (int i = 0; i < 4; ++i)
        tile[ty + i * 8][tx] = in[(size_t)(r0 + ty + i * 8) * C + c0 + tx];
    __syncthreads();
    #pragma unroll
    for (int i = 0; i < 4; ++i)
        out[(size_t)(c0 + ty + i * 8) * R + r0 + tx] = (f16)tile[tx][ty + i * 8];
}

// ---------------------------------------------------------------------------
// MFMA GEMM: C(M x N) = A(M x K) @ Bt(N x K)^T + bias
// 128x128 tile, BK=32, 256 threads, fp16 in, fp32 acc.
// MODE 0 epilogue (QKV proj): Q -> [b][h][n][d] plain
//                             K -> [b][h][n][d] with d-chunk8 XOR (n&7) swizzle
//                             V -> [b][h][d][n] transposed, n-chunk8 XOR (d&7) swizzle
// MODE 1 epilogue: fp32 row-major C with bias
// ---------------------------------------------------------------------------
template<int MODE>
__global__ __launch_bounds__(256)
void gemm_mfma(const f16* __restrict__ A, const f16* __restrict__ Bt,
               const float* __restrict__ bias, int N, int K,
               float* __restrict__ Cout,
               f16* __restrict__ qb, f16* __restrict__ kb, f16* __restrict__ vb)
{
    __shared__ f16 As[128 * 32];
    __shared__ f16 Bs[128 * 32];
    const int t = threadIdx.x;
    const int lane = t & 63, w = t >> 6;
    const int quad = lane >> 4, l16 = lane & 15;
    const int m0 = blockIdx.y * 128, n0 = blockIdx.x * 128;
    const int wm = (w & 1) * 64, wn = (w >> 1) * 64;

    f32x4 acc[4][4];
    #pragma unroll
    for (int i = 0; i < 4; ++i)
        #pragma unroll
        for (int j = 0; j < 4; ++j)
            acc[i][j] = f32x4{0.f, 0.f, 0.f, 0.f};

    const int srow = t >> 2, scol = (t & 3) * 8;
    const f16* agp = A  + (size_t)(m0 + srow) * K + scol;
    const f16* bgp = Bt + (size_t)(n0 + srow) * K + scol;
    f16* alds = As + w * 512;
    f16* blds = Bs + w * 512;

    for (int k0 = 0; k0 < K; k0 += 32) {
        __syncthreads();
        gll16(agp + k0,          alds);
        gll16(agp + k0 + 64 * K, alds + 2048);
        gll16(bgp + k0,          blds);
        gll16(bgp + k0 + 64 * K, blds + 2048);
        __syncthreads();

        f16x8 af[4], bf[4];
        #pragma unroll
        for (int ms = 0; ms < 4; ++ms)
            af[ms] = *(const f16x8*)&As[(wm + ms * 16 + l16) * 32 + quad * 8];
        #pragma unroll
        for (int ns = 0; ns < 4; ++ns)
            bf[ns] = *(const f16x8*)&Bs[(wn + ns * 16 + l16) * 32 + quad * 8];
        #pragma unroll
        for (int ms = 0; ms < 4; ++ms)
            #pragma unroll
            for (int ns = 0; ns < 4; ++ns)
                acc[ms][ns] = __builtin_amdgcn_mfma_f32_16x16x32_f16(
                    af[ms], bf[ns], acc[ms][ns], 0, 0, 0);
    }

    // C/D layout: col = l16 (n), row = quad*4 + reg (m)
    if (MODE == 0) {
        #pragma unroll
        for (int ns = 0; ns < 4; ++ns) {
            int col = n0 + wn + ns * 16 + l16;
            float bv = bias[col];
            int which = col >> 10;
            int hh = (col & 1023) >> 6, d = col & 63;
            #pragma unroll
            for (int ms = 0; ms < 4; ++ms) {
                int rowb = m0 + wm + ms * 16 + quad * 4;
                int bb_ = rowb >> 9, n_ = rowb & 511;   // same over 4 regs (rowb%4==0)
                if (which == 2) {
                    // V: [b][h][d][n], n-chunk8 XOR (d&7), f16x4 over 4 consecutive n
                    f16x4 pk;
                    #pragma unroll
                    for (int reg = 0; reg < 4; ++reg)
                        pk[reg] = (f16)(acc[ms][ns][reg] + bv);
                    int c8s = ((n_ >> 3) & 7) ^ (d & 7);
                    f16* dst = vb + ((size_t)(bb_ * NH + hh) * DH + d) * SEQ
                                  + (n_ & ~63) + c8s * 8 + (n_ & 7);
                    *(f16x4*)dst = pk;
                } else if (which == 1) {
                    // K: [b][h][n][d], d-chunk8 XOR (n&7)
                    #pragma unroll
                    for (int reg = 0; reg < 4; ++reg) {
                        int n = n_ + reg;
                        int dd = (((d >> 3) ^ (n & 7)) * 8) + (d & 7);
                        kb[((size_t)(bb_ * NH + hh) * SEQ + n) * DH + dd] =
                            (f16)(acc[ms][ns][reg] + bv);
                    }
                } else {
                    #pragma unroll
                    for (int reg = 0; reg < 4; ++reg)
                        qb[((size_t)(bb_ * NH + hh) * SEQ + n_ + reg) * DH + d] =
                            (f16)(acc[ms][ns][reg] + bv);
                }
            }
        }
    } else {
        #pragma unroll
        for (int ns = 0; ns < 4; ++ns) {
            int col = n0 + wn + ns * 16 + l16;
            float bv = bias[col];
            #pragma unroll
            for (int ms = 0; ms < 4; ++ms) {
                int rowb = m0 + wm + ms * 16 + quad * 4;
                #pragma unroll
                for (int reg = 0; reg < 4; ++reg)
                    Cout[(size_t)(rowb + reg) * N + col] = acc[ms][ns][reg] + bv;
            }
        }
    }
}

// ---------------------------------------------------------------------------
// MFMA flash attention, transposed-S formulation, no online rescale.
// Block = (b, h, 64 q-rows); 4 waves x 16 q-rows; 8 key tiles of 64.
// S^T = mfma(K_frag, Q_frag): lane holds S[key=quad*4+reg (+mt*16)][q=l16]
//   -> all of a lane's p-values share one q row -> per-lane scalar l-sum,
//      reduced across quads ONCE at the end (2 shuffles total).
// p = exp2(s*0.125*log2e + bias*log2e); no max subtraction (|s| << 11).
// K/V staged by global_load_lds from XOR-swizzled global layouts; all LDS
// fragment reads 2-way (free). P: 4x ds_write_b64 (optimal) + 2x b128 reads.
// ---------------------------------------------------------------------------
__global__ __launch_bounds__(256)
void attn_mfma(const f16* __restrict__ qb, const f16* __restrict__ kb,
               const f16* __restrict__ vb, const float* __restrict__ rel,
               f16* __restrict__ ob)
{
    __shared__ f16 Ks[64 * 64];       // [key][d-chunks XOR key&7]
    __shared__ f16 Vt[64 * 64];       // [d][key-chunks XOR d&7]
    __shared__ f16 Pw[4][16 * 64];    // wave-private [q][key-chunks XOR q&7]
    __shared__ float relh[1024];      // rel[:,h] * log2(e)

    const int t = threadIdx.x;
    const int lane = t & 63, w = t >> 6;
    const int quad = lane >> 4, l16 = lane & 15;
    const int bid = blockIdx.x;
    const int bh = bid & 255, qt = bid >> 8;   // qt slow -> same (b,h) shares XCD
    const int h = bh & 15, b = bh >> 4;

    for (int i = t; i < 2 * MAXL - 1; i += 256)
        relh[i] = rel[i * NH + h] * 1.44269504f;

    // Q B-fragments: lane -> Q[q=w*16+l16][d=quad*8+j (+32)]
    const f16* qrow = qb + ((size_t)bh * SEQ + qt * 64 + w * 16 + l16) * DH + quad * 8;
    f16x8 qf0 = *(const f16x8*)(qrow);
    f16x8 qf1 = *(const f16x8*)(qrow + 32);

    f32x4 o[4];
    #pragma unroll
    for (int dt = 0; dt < 4; ++dt) o[dt] = f32x4{0.f, 0.f, 0.f, 0.f};
    float lsum = 0.f;

    // staging pointers (per-lane global addr; wave-uniform LDS dest)
    const f16* kpl = kb + (size_t)bh * SEQ * DH
                   + (size_t)(w * 16 + (lane >> 3)) * DH + (lane & 7) * 8;
    const f16* vpl = vb + (size_t)bh * DH * SEQ
                   + (size_t)(w * 16 + (lane >> 3)) * SEQ + (lane & 7) * 8;
    f16* kdst = Ks + w * 1024;
    f16* vdst = Vt + w * 1024;

    const int xr = l16 & 7;            // row-xor for this lane's fragment reads
    const int i0 = qt * 64 + w * 16 + l16;   // this lane's q row (global)

    for (int kt = 0; kt < 8; ++kt) {
        __syncthreads();
        gll16(kpl + kt * 64 * DH,          kdst);
        gll16(kpl + kt * 64 * DH + 8 * DH, kdst + 512);
        gll16(vpl + kt * 64,               vdst);
        gll16(vpl + kt * 64 + 8 * SEQ,     vdst + 512);
        __syncthreads();

        // ---- S^T = K Q^T : rows = key, cols = q ----
        f32x4 sT[4];
        #pragma unroll
        for (int mt = 0; mt < 4; ++mt) {
            const f16* kr = &Ks[(mt * 16 + l16) * 64];
            f16x8 a0 = *(const f16x8*)(kr + ((quad ^ xr) * 8));
            f16x8 a1 = *(const f16x8*)(kr + (((4 + quad) ^ xr) * 8));
            f32x4 c = f32x4{0.f, 0.f, 0.f, 0.f};
            c = __builtin_amdgcn_mfma_f32_16x16x32_f16(a0, qf0, c, 0, 0, 0);
            c = __builtin_amdgcn_mfma_f32_16x16x32_f16(a1, qf1, c, 0, 0, 0);
            sT[mt] = c;
        }

        // ---- p = exp2(s*0.125*log2e + bias), accumulate row-sum in register ----
        const int cbase = i0 + (MAXL - 1) - kt * 64 - quad * 4;
        f16* pw = &Pw[w][0];
        #pragma unroll
        for (int mt = 0; mt < 4; ++mt) {
            f16x4 pk;
            #pragma unroll
            for (int reg = 0; reg < 4; ++reg) {
                float e = exp2f(fmaf(sT[mt][reg], 0.180336878f,
                                     relh[cbase - mt * 16 - reg]));
                lsum += e;
                pk[reg] = (f16)e;
            }
            // key = mt*16 + quad*4 + reg; chunk8 = mt*2 + (quad>>1), XOR q&7
            int c8 = (mt * 2 + (quad >> 1)) ^ xr;
            *(f16x4*)&pw[l16 * 64 + c8 * 8 + (quad & 1) * 4] = pk;
        }
        __builtin_amdgcn_s_waitcnt(0xC07F);   // lgkmcnt(0): P visible within wave

        // ---- O += P V ----
        #pragma unroll
        for (int s2 = 0; s2 < 2; ++s2) {
            f16x8 pa = *(const f16x8*)&pw[l16 * 64 + (((s2 * 4 + quad) ^ xr) * 8)];
            #pragma unroll
            for (int dt = 0; dt < 4; ++dt) {
                const f16* vr = &Vt[(dt * 16 + l16) * 64];
                f16x8 vb8 = *(const f16x8*)(vr + (((s2 * 4 + quad) ^ xr) * 8));
                o[dt] = __builtin_amdgcn_mfma_f32_16x16x32_f16(pa, vb8, o[dt], 0, 0, 0);
            }
        }
    }

    // ---- final row-sum reduce (across quads) + normalize + write ----
    lsum += __shfl_xor(lsum, 16, 64);
    lsum += __shfl_xor(lsum, 32, 64);
    // lane holds O[q_local=quad*4+reg][d=dt*16+l16]; fetch that row's sum
    #pragma unroll
    for (int reg = 0; reg < 4; ++reg) {
        float inv = 1.0f / __shfl(lsum, quad * 4 + reg, 64);
        size_t rbase = ((size_t)b * SEQ + qt * 64 + w * 16 + quad * 4 + reg) * DMODEL
                     + h * DH;
        #pragma unroll
        for (int dt = 0; dt < 4; ++dt)
            ob[rbase + dt * 16 + l16] = (f16)(o[dt][reg] * inv);
    }
}

// ---------------------------------------------------------------------------
extern "C" void kernel_launch(void* const* d_in, const int* in_sizes, int n_in,
                              void* d_out, int out_size, void* d_ws, size_t ws_size,
                              hipStream_t stream)
{
    const float* x    = (const float*)d_in[0];
    const float* wqkv = (const float*)d_in[1];
    const float* bqkv = (const float*)d_in[2];
    const float* rel  = (const float*)d_in[3];
    const float* wout = (const float*)d_in[4];
    const float* bout = (const float*)d_in[5];
    float* out = (float*)d_out;
    char* ws = (char*)d_ws;

    const size_t XH = (size_t)MROWS * DMODEL;            // 8M elements
    f16* xh    = (f16*)(ws);                             // 16 MB
    f16* wqkvT = (f16*)(ws + 2 * XH);                    // 6 MB
    f16* woutT = wqkvT + (size_t)3 * DMODEL * DMODEL;    // 2 MB
    f16* qbuf  = woutT + (size_t)DMODEL * DMODEL;
    f16* kbuf  = qbuf + XH;
    f16* vbuf  = kbuf + XH;
    f16* abuf  = vbuf + XH;

    cvt_f32_f16<<<XH / 1024, 256, 0, stream>>>(x, xh, (int)XH);
    transpose_cvt<<<dim3(3 * DMODEL / 32, DMODEL / 32), dim3(32, 8), 0, stream>>>(
        wqkv, wqkvT, DMODEL, 3 * DMODEL);
    transpose_cvt<<<dim3(DMODEL / 32, DMODEL / 32), dim3(32, 8), 0, stream>>>(
        wout, woutT, DMODEL, DMODEL);

    gemm_mfma<0><<<dim3(3 * DMODEL / 128, MROWS / 128), 256, 0, stream>>>(
        xh, wqkvT, bqkv, 3 * DMODEL, DMODEL, nullptr, qbuf, kbuf, vbuf);

    attn_mfma<<<dim3(NB * NH * (SEQ / 64)), 256, 0, stream>>>(
        qbuf, kbuf, vbuf, rel, abuf);

    gemm_mfma<1><<<dim3(DMODEL / 128, MROWS / 128), 256, 0, stream>>>(
        abuf, woutT, bout, DMODEL, DMODEL, out, nullptr, nullptr, nullptr);
}

// Round 4
// 239.497 us; speedup vs baseline: 5.0848x; 1.0514x over previous
//
#include <hip/hip_runtime.h>

#define SEQ    512
#define NH     16
#define DH     64
#define DMODEL 1024
#define NB     16
#define MROWS  (NB*SEQ)      // 8192
#define MAXL   512

typedef _Float16 f16;
typedef f16  f16x8 __attribute__((ext_vector_type(8)));
typedef f16  f16x4 __attribute__((ext_vector_type(4)));
typedef float f32x4 __attribute__((ext_vector_type(4)));

// async global->LDS, 16B/lane; global addr per-lane, LDS dest = wave-uniform base + lane*16
__device__ static inline void gll16(const f16* g, f16* l) {
    __builtin_amdgcn_global_load_lds(
        (const __attribute__((address_space(1))) void*)(g),
        (__attribute__((address_space(3))) void*)(l), 16, 0, 0);
}

// ---------------------------------------------------------------------------
// fused prep: x -> f16 (blocks 0..8191), wqkv -> f16 transposed (8192..11263),
// wout -> f16 transposed (11264..12287)
// ---------------------------------------------------------------------------
__global__ __launch_bounds__(256)
void prep(const float* __restrict__ x, f16* __restrict__ xh,
          const float* __restrict__ wqkv, f16* __restrict__ wqkvT,
          const float* __restrict__ wout, f16* __restrict__ woutT)
{
    const int bid = blockIdx.x, t = threadIdx.x;
    if (bid < 8192) {
        int i = (bid * 256 + t) * 4;
        float4 v = *(const float4*)(x + i);
        f16x4 h = { (f16)v.x, (f16)v.y, (f16)v.z, (f16)v.w };
        *(f16x4*)(xh + i) = h;
        return;
    }
    __shared__ float tile[32][33];
    const float* in; f16* out; int C, gx, gy;
    if (bid < 8192 + 3072) {
        int b2 = bid - 8192; in = wqkv; out = wqkvT; C = 3072;
        gx = b2 % 96; gy = b2 / 96;
    } else {
        int b2 = bid - 11264; in = wout; out = woutT; C = 1024;
        gx = b2 & 31; gy = b2 >> 5;
    }
    const int R = 1024;
    int tx = t & 31, ty = t >> 5;
    int c0 = gx * 32, r0 = gy * 32;
    #pragma unroll
    for (int i = 0; i < 4; ++i)
        tile[ty + i * 8][tx] = in[(size_t)(r0 + ty + i * 8) * C + c0 + tx];
    __syncthreads();
    #pragma unroll
    for (int i = 0; i < 4; ++i)
        out[(size_t)(c0 + ty + i * 8) * R + r0 + tx] = (f16)tile[tx][ty + i * 8];
}

// ---------------------------------------------------------------------------
// MFMA GEMM: C(M x N) = A(M x K) @ Bt(N x K)^T + bias
// 128x128 tile, BK=64, 256 threads, fp16 in, fp32 acc.
// Staging XOR-swizzle: lane fetches global chunk (lane&7)^(lane>>3) so the
// forced-contiguous global_load_lds dest yields LDS[row][c8 ^ (row&7)] ->
// fragment ds_read_b128 land 2-way (free) on all 32 banks.
// MODE 0 epilogue (QKV): Q -> [b][h][d][n] transposed, f16x4 over n
//                        K -> [b][h][n][d], d-chunk8 XOR (n&7)
//                        V -> [b][h][d][n] transposed, n-chunk8 XOR (d&7)
// MODE 1 epilogue: fp32 row-major C + bias
// ---------------------------------------------------------------------------
template<int MODE>
__global__ __launch_bounds__(256)
void gemm_mfma(const f16* __restrict__ A, const f16* __restrict__ Bt,
               const float* __restrict__ bias, int N, int K,
               float* __restrict__ Cout,
               f16* __restrict__ qb, f16* __restrict__ kb, f16* __restrict__ vb)
{
    __shared__ f16 As[128 * 64];   // 16 KB
    __shared__ f16 Bs[128 * 64];   // 16 KB
    const int t = threadIdx.x;
    const int lane = t & 63, w = t >> 6;
    const int quad = lane >> 4, l16 = lane & 15;
    const int xr = l16 & 7;
    const int m0 = blockIdx.y * 128, n0 = blockIdx.x * 128;
    const int wm = (w & 1) * 64, wn = (w >> 1) * 64;

    f32x4 acc[4][4];
    #pragma unroll
    for (int i = 0; i < 4; ++i)
        #pragma unroll
        for (int j = 0; j < 4; ++j)
            acc[i][j] = f32x4{0.f, 0.f, 0.f, 0.f};

    // staging: wave w, call c -> rows w*32 + c*8 + (lane>>3), chunk (lane&7)^(lane>>3)
    const int sr8 = lane >> 3;
    const int sc8 = (lane & 7) ^ sr8;
    const f16* agp = A  + (size_t)(m0 + w * 32 + sr8) * K + sc8 * 8;
    const f16* bgp = Bt + (size_t)(n0 + w * 32 + sr8) * K + sc8 * 8;
    f16* asl = As + w * 2048;
    f16* bsl = Bs + w * 2048;

    for (int k0 = 0; k0 < K; k0 += 64) {
        __syncthreads();
        #pragma unroll
        for (int c = 0; c < 4; ++c) {
            gll16(agp + k0 + c * 8 * K, asl + c * 512);
            gll16(bgp + k0 + c * 8 * K, bsl + c * 512);
        }
        __syncthreads();
        #pragma unroll
        for (int ks = 0; ks < 2; ++ks) {
            f16x8 af[4], bf[4];
            #pragma unroll
            for (int ms = 0; ms < 4; ++ms)
                af[ms] = *(const f16x8*)&As[(wm + ms * 16 + l16) * 64
                                            + (((ks * 4 + quad) ^ xr) * 8)];
            #pragma unroll
            for (int ns = 0; ns < 4; ++ns)
                bf[ns] = *(const f16x8*)&Bs[(wn + ns * 16 + l16) * 64
                                            + (((ks * 4 + quad) ^ xr) * 8)];
            #pragma unroll
            for (int ms = 0; ms < 4; ++ms)
                #pragma unroll
                for (int ns = 0; ns < 4; ++ns)
                    acc[ms][ns] = __builtin_amdgcn_mfma_f32_16x16x32_f16(
                        af[ms], bf[ns], acc[ms][ns], 0, 0, 0);
        }
    }

    // C/D layout: col = l16 (n), row = quad*4 + reg (m)
    if (MODE == 0) {
        #pragma unroll
        for (int ns = 0; ns < 4; ++ns) {
            int col = n0 + wn + ns * 16 + l16;
            float bv = bias[col];
            int which = col >> 10;
            int hh = (col & 1023) >> 6, d = col & 63;
            #pragma unroll
            for (int ms = 0; ms < 4; ++ms) {
                int rowb = m0 + wm + ms * 16 + quad * 4;
                int bb_ = rowb >> 9, n_ = rowb & 511;   // rowb%4==0
                if (which == 0) {
                    // Q: transposed [b][h][d][n], vectorized over n
                    f16x4 pk;
                    #pragma unroll
                    for (int reg = 0; reg < 4; ++reg)
                        pk[reg] = (f16)(acc[ms][ns][reg] + bv);
                    *(f16x4*)(qb + ((size_t)(bb_ * NH + hh) * DH + d) * SEQ + n_) = pk;
                } else if (which == 2) {
                    // V: transposed [b][h][d][n], n-chunk8 XOR (d&7)
                    f16x4 pk;
                    #pragma unroll
                    for (int reg = 0; reg < 4; ++reg)
                        pk[reg] = (f16)(acc[ms][ns][reg] + bv);
                    int c8s = ((n_ >> 3) & 7) ^ (d & 7);
                    *(f16x4*)(vb + ((size_t)(bb_ * NH + hh) * DH + d) * SEQ
                                 + (n_ & ~63) + c8s * 8 + (n_ & 7)) = pk;
                } else {
                    // K: [b][h][n][d], d-chunk8 XOR (n&7)
                    #pragma unroll
                    for (int reg = 0; reg < 4; ++reg) {
                        int n = n_ + reg;
                        int dd = (((d >> 3) ^ (n & 7)) * 8) + (d & 7);
                        kb[((size_t)(bb_ * NH + hh) * SEQ + n) * DH + dd] =
                            (f16)(acc[ms][ns][reg] + bv);
                    }
                }
            }
        }
    } else {
        #pragma unroll
        for (int ns = 0; ns < 4; ++ns) {
            int col = n0 + wn + ns * 16 + l16;
            float bv = bias[col];
            #pragma unroll
            for (int ms = 0; ms < 4; ++ms) {
                int rowb = m0 + wm + ms * 16 + quad * 4;
                #pragma unroll
                for (int reg = 0; reg < 4; ++reg)
                    Cout[(size_t)(rowb + reg) * N + col] = acc[ms][ns][reg] + bv;
            }
        }
    }
}

// ---------------------------------------------------------------------------
// MFMA flash attention, transposed-S, no online rescale (|s| << f16 overflow).
// Block = (b, h, 64 q-rows); 4 waves x 16 q-rows; 8 key tiles of 64.
// S^T = mfma(K_frag, Q_frag): lane's 16 p-values share one q-row -> scalar
// l-sum in register, reduced across quads once at the end.
// K/V staged via global_load_lds from XOR-swizzled global layouts.
// ---------------------------------------------------------------------------
__global__ __launch_bounds__(256)
void attn_mfma(const f16* __restrict__ qb, const f16* __restrict__ kb,
               const f16* __restrict__ vb, const float* __restrict__ rel,
               f16* __restrict__ ob)
{
    __shared__ f16 Ks[64 * 64];
    __shared__ f16 Vt[64 * 64];
    __shared__ f16 Pw[4][16 * 64];
    __shared__ float relh[1024];

    const int t = threadIdx.x;
    const int lane = t & 63, w = t >> 6;
    const int quad = lane >> 4, l16 = lane & 15;
    const int bid = blockIdx.x;
    const int bh = bid & 255, qt = bid >> 8;
    const int h = bh & 15, b = bh >> 4;

    for (int i = t; i < 2 * MAXL - 1; i += 256)
        relh[i] = rel[i * NH + h] * 1.44269504f;

    // Q B-fragments from transposed [b][h][d][n]: lane -> Q[q=w*16+l16][d=quad*8+j]
    const f16* qbase = qb + (size_t)bh * DH * SEQ + (qt * 64 + w * 16 + l16);
    f16x8 qf0, qf1;
    #pragma unroll
    for (int j = 0; j < 8; ++j) {
        qf0[j] = qbase[(quad * 8 + j) * SEQ];
        qf1[j] = qbase[(quad * 8 + j + 32) * SEQ];
    }

    f32x4 o[4];
    #pragma unroll
    for (int dt = 0; dt < 4; ++dt) o[dt] = f32x4{0.f, 0.f, 0.f, 0.f};
    float lsum = 0.f;

    const f16* kpl = kb + (size_t)bh * SEQ * DH
                   + (size_t)(w * 16 + (lane >> 3)) * DH + (lane & 7) * 8;
    const f16* vpl = vb + (size_t)bh * DH * SEQ
                   + (size_t)(w * 16 + (lane >> 3)) * SEQ + (lane & 7) * 8;
    f16* kdst = Ks + w * 1024;
    f16* vdst = Vt + w * 1024;

    const int xr = l16 & 7;
    const int i0 = qt * 64 + w * 16 + l16;

    for (int kt = 0; kt < 8; ++kt) {
        __syncthreads();
        gll16(kpl + kt * 64 * DH,          kdst);
        gll16(kpl + kt * 64 * DH + 8 * DH, kdst + 512);
        gll16(vpl + kt * 64,               vdst);
        gll16(vpl + kt * 64 + 8 * SEQ,     vdst + 512);
        __syncthreads();

        // ---- S^T = K Q^T ----
        f32x4 sT[4];
        #pragma unroll
        for (int mt = 0; mt < 4; ++mt) {
            const f16* kr = &Ks[(mt * 16 + l16) * 64];
            f16x8 a0 = *(const f16x8*)(kr + ((quad ^ xr) * 8));
            f16x8 a1 = *(const f16x8*)(kr + (((4 + quad) ^ xr) * 8));
            f32x4 c = f32x4{0.f, 0.f, 0.f, 0.f};
            c = __builtin_amdgcn_mfma_f32_16x16x32_f16(a0, qf0, c, 0, 0, 0);
            c = __builtin_amdgcn_mfma_f32_16x16x32_f16(a1, qf1, c, 0, 0, 0);
            sT[mt] = c;
        }

        // ---- p = exp2(s*scale*log2e + bias), register row-sum ----
        const int cbase = i0 + (MAXL - 1) - kt * 64 - quad * 4;
        f16* pw = &Pw[w][0];
        #pragma unroll
        for (int mt = 0; mt < 4; ++mt) {
            f16x4 pk;
            #pragma unroll
            for (int reg = 0; reg < 4; ++reg) {
                float e = exp2f(fmaf(sT[mt][reg], 0.180336878f,
                                     relh[cbase - mt * 16 - reg]));
                lsum += e;
                pk[reg] = (f16)e;
            }
            int c8 = (mt * 2 + (quad >> 1)) ^ xr;
            *(f16x4*)&pw[l16 * 64 + c8 * 8 + (quad & 1) * 4] = pk;
        }
        __builtin_amdgcn_s_waitcnt(0xC07F);   // lgkmcnt(0)

        // ---- O += P V ----
        #pragma unroll
        for (int s2 = 0; s2 < 2; ++s2) {
            f16x8 pa = *(const f16x8*)&pw[l16 * 64 + (((s2 * 4 + quad) ^ xr) * 8)];
            #pragma unroll
            for (int dt = 0; dt < 4; ++dt) {
                const f16* vr = &Vt[(dt * 16 + l16) * 64];
                f16x8 vb8 = *(const f16x8*)(vr + (((s2 * 4 + quad) ^ xr) * 8));
                o[dt] = __builtin_amdgcn_mfma_f32_16x16x32_f16(pa, vb8, o[dt], 0, 0, 0);
            }
        }
    }

    lsum += __shfl_xor(lsum, 16, 64);
    lsum += __shfl_xor(lsum, 32, 64);
    #pragma unroll
    for (int reg = 0; reg < 4; ++reg) {
        float inv = 1.0f / __shfl(lsum, quad * 4 + reg, 64);
        size_t rbase = ((size_t)b * SEQ + qt * 64 + w * 16 + quad * 4 + reg) * DMODEL
                     + h * DH;
        #pragma unroll
        for (int dt = 0; dt < 4; ++dt)
            ob[rbase + dt * 16 + l16] = (f16)(o[dt][reg] * inv);
    }
}

// ---------------------------------------------------------------------------
extern "C" void kernel_launch(void* const* d_in, const int* in_sizes, int n_in,
                              void* d_out, int out_size, void* d_ws, size_t ws_size,
                              hipStream_t stream)
{
    const float* x    = (const float*)d_in[0];
    const float* wqkv = (const float*)d_in[1];
    const float* bqkv = (const float*)d_in[2];
    const float* rel  = (const float*)d_in[3];
    const float* wout = (const float*)d_in[4];
    const float* bout = (const float*)d_in[5];
    float* out = (float*)d_out;
    char* ws = (char*)d_ws;

    const size_t XH = (size_t)MROWS * DMODEL;            // 8M elements
    f16* xh    = (f16*)(ws);
    f16* wqkvT = (f16*)(ws + 2 * XH);
    f16* woutT = wqkvT + (size_t)3 * DMODEL * DMODEL;
    f16* qbuf  = woutT + (size_t)DMODEL * DMODEL;
    f16* kbuf  = qbuf + XH;
    f16* vbuf  = kbuf + XH;
    f16* abuf  = vbuf + XH;

    prep<<<12288, 256, 0, stream>>>(x, xh, wqkv, wqkvT, wout, woutT);

    gemm_mfma<0><<<dim3(3 * DMODEL / 128, MROWS / 128), 256, 0, stream>>>(
        xh, wqkvT, bqkv, 3 * DMODEL, DMODEL, nullptr, qbuf, kbuf, vbuf);

    attn_mfma<<<dim3(NB * NH * (SEQ / 64)), 256, 0, stream>>>(
        qbuf, kbuf, vbuf, rel, abuf);

    gemm_mfma<1><<<dim3(DMODEL / 128, MROWS / 128), 256, 0, stream>>>(
        abuf, woutT, bout, DMODEL, DMODEL, out, nullptr, nullptr, nullptr);
}

// Round 5
// 230.081 us; speedup vs baseline: 5.2929x; 1.0409x over previous
//
#include <hip/hip_runtime.h>

#define SEQ    512
#define NH     16
#define DH     64
#define DMODEL 1024
#define NB     16
#define MROWS  (NB*SEQ)      // 8192
#define MAXL   512

typedef _Float16 f16;
typedef f16  f16x8 __attribute__((ext_vector_type(8)));
typedef f16  f16x4 __attribute__((ext_vector_type(4)));
typedef float f32x4 __attribute__((ext_vector_type(4)));

// async global->LDS, 16B/lane; global addr per-lane, LDS dest = wave-uniform base + lane*16
__device__ static inline void gll16(const f16* g, f16* l) {
    __builtin_amdgcn_global_load_lds(
        (const __attribute__((address_space(1))) void*)(g),
        (__attribute__((address_space(3))) void*)(l), 16, 0, 0);
}

// ---------------------------------------------------------------------------
// fused prep: x -> f16 (blocks 0..8191), wqkv -> f16 transposed (8192..11263),
// wout -> f16 transposed (11264..12287)
// ---------------------------------------------------------------------------
__global__ __launch_bounds__(256)
void prep(const float* __restrict__ x, f16* __restrict__ xh,
          const float* __restrict__ wqkv, f16* __restrict__ wqkvT,
          const float* __restrict__ wout, f16* __restrict__ woutT)
{
    const int bid = blockIdx.x, t = threadIdx.x;
    if (bid < 8192) {
        int i = (bid * 256 + t) * 4;
        float4 v = *(const float4*)(x + i);
        f16x4 h = { (f16)v.x, (f16)v.y, (f16)v.z, (f16)v.w };
        *(f16x4*)(xh + i) = h;
        return;
    }
    __shared__ float tile[32][33];
    const float* in; f16* out; int C, gx, gy;
    if (bid < 8192 + 3072) {
        int b2 = bid - 8192; in = wqkv; out = wqkvT; C = 3072;
        gx = b2 % 96; gy = b2 / 96;
    } else {
        int b2 = bid - 11264; in = wout; out = woutT; C = 1024;
        gx = b2 & 31; gy = b2 >> 5;
    }
    const int R = 1024;
    int tx = t & 31, ty = t >> 5;
    int c0 = gx * 32, r0 = gy * 32;
    #pragma unroll
    for (int i = 0; i < 4; ++i)
        tile[ty + i * 8][tx] = in[(size_t)(r0 + ty + i * 8) * C + c0 + tx];
    __syncthreads();
    #pragma unroll
    for (int i = 0; i < 4; ++i)
        out[(size_t)(c0 + ty + i * 8) * R + r0 + tx] = (f16)tile[tx][ty + i * 8];
}

// ---------------------------------------------------------------------------
// MFMA GEMM: C(M x N) = A(M x K) @ Bt(N x K)^T + bias
// 128x128 tile, BK=64, 256 threads, fp16 in, fp32 acc.
// Staging XOR-swizzle: lane fetches global chunk (lane&7)^(lane>>3) so the
// forced-contiguous global_load_lds dest yields LDS[row][c8 ^ (row&7)] ->
// fragment ds_read_b128 are 2-way (free).
// MODE 0 epilogue (QKV): Q -> [b][h][n][d] plain (vector attn loads)
//                        K -> [b][h][n][d], d-chunk8 XOR (n&7)
//                        V -> [b][h][d][n] transposed, n-chunk8 XOR (d&7)
// MODE 1 epilogue: fp32 row-major C + bias
// ---------------------------------------------------------------------------
template<int MODE>
__global__ __launch_bounds__(256)
void gemm_mfma(const f16* __restrict__ A, const f16* __restrict__ Bt,
               const float* __restrict__ bias, int N, int K,
               float* __restrict__ Cout,
               f16* __restrict__ qb, f16* __restrict__ kb, f16* __restrict__ vb)
{
    __shared__ f16 As[128 * 64];
    __shared__ f16 Bs[128 * 64];
    const int t = threadIdx.x;
    const int lane = t & 63, w = t >> 6;
    const int quad = lane >> 4, l16 = lane & 15;
    const int xr = l16 & 7;
    const int m0 = blockIdx.y * 128, n0 = blockIdx.x * 128;
    const int wm = (w & 1) * 64, wn = (w >> 1) * 64;

    f32x4 acc[4][4];
    #pragma unroll
    for (int i = 0; i < 4; ++i)
        #pragma unroll
        for (int j = 0; j < 4; ++j)
            acc[i][j] = f32x4{0.f, 0.f, 0.f, 0.f};

    const int sr8 = lane >> 3;
    const int sc8 = (lane & 7) ^ sr8;
    const f16* agp = A  + (size_t)(m0 + w * 32 + sr8) * K + sc8 * 8;
    const f16* bgp = Bt + (size_t)(n0 + w * 32 + sr8) * K + sc8 * 8;
    f16* asl = As + w * 2048;
    f16* bsl = Bs + w * 2048;

    for (int k0 = 0; k0 < K; k0 += 64) {
        __syncthreads();
        #pragma unroll
        for (int c = 0; c < 4; ++c) {
            gll16(agp + k0 + c * 8 * K, asl + c * 512);
            gll16(bgp + k0 + c * 8 * K, bsl + c * 512);
        }
        __syncthreads();
        #pragma unroll
        for (int ks = 0; ks < 2; ++ks) {
            f16x8 af[4], bf[4];
            #pragma unroll
            for (int ms = 0; ms < 4; ++ms)
                af[ms] = *(const f16x8*)&As[(wm + ms * 16 + l16) * 64
                                            + (((ks * 4 + quad) ^ xr) * 8)];
            #pragma unroll
            for (int ns = 0; ns < 4; ++ns)
                bf[ns] = *(const f16x8*)&Bs[(wn + ns * 16 + l16) * 64
                                            + (((ks * 4 + quad) ^ xr) * 8)];
            #pragma unroll
            for (int ms = 0; ms < 4; ++ms)
                #pragma unroll
                for (int ns = 0; ns < 4; ++ns)
                    acc[ms][ns] = __builtin_amdgcn_mfma_f32_16x16x32_f16(
                        af[ms], bf[ns], acc[ms][ns], 0, 0, 0);
        }
    }

    // C/D layout: col = l16 (n), row = quad*4 + reg (m)
    if (MODE == 0) {
        #pragma unroll
        for (int ns = 0; ns < 4; ++ns) {
            int col = n0 + wn + ns * 16 + l16;
            float bv = bias[col];
            int which = col >> 10;
            int hh = (col & 1023) >> 6, d = col & 63;
            #pragma unroll
            for (int ms = 0; ms < 4; ++ms) {
                int rowb = m0 + wm + ms * 16 + quad * 4;
                int bb_ = rowb >> 9, n_ = rowb & 511;   // rowb%4==0
                if (which == 0) {
                    // Q: plain [b][h][n][d]
                    #pragma unroll
                    for (int reg = 0; reg < 4; ++reg)
                        qb[((size_t)(bb_ * NH + hh) * SEQ + n_ + reg) * DH + d] =
                            (f16)(acc[ms][ns][reg] + bv);
                } else if (which == 2) {
                    // V: transposed [b][h][d][n], n-chunk8 XOR (d&7)
                    f16x4 pk;
                    #pragma unroll
                    for (int reg = 0; reg < 4; ++reg)
                        pk[reg] = (f16)(acc[ms][ns][reg] + bv);
                    int c8s = ((n_ >> 3) & 7) ^ (d & 7);
                    *(f16x4*)(vb + ((size_t)(bb_ * NH + hh) * DH + d) * SEQ
                                 + (n_ & ~63) + c8s * 8 + (n_ & 7)) = pk;
                } else {
                    // K: [b][h][n][d], d-chunk8 XOR (n&7)
                    #pragma unroll
                    for (int reg = 0; reg < 4; ++reg) {
                        int n = n_ + reg;
                        int dd = (((d >> 3) ^ (n & 7)) * 8) + (d & 7);
                        kb[((size_t)(bb_ * NH + hh) * SEQ + n) * DH + dd] =
                            (f16)(acc[ms][ns][reg] + bv);
                    }
                }
            }
        }
    } else {
        #pragma unroll
        for (int ns = 0; ns < 4; ++ns) {
            int col = n0 + wn + ns * 16 + l16;
            float bv = bias[col];
            #pragma unroll
            for (int ms = 0; ms < 4; ++ms) {
                int rowb = m0 + wm + ms * 16 + quad * 4;
                #pragma unroll
                for (int reg = 0; reg < 4; ++reg)
                    Cout[(size_t)(rowb + reg) * N + col] = acc[ms][ns][reg] + bv;
            }
        }
    }
}

// ---------------------------------------------------------------------------
// MFMA attention, one block per (b,h). 512 threads = 8 waves; wave w owns
// q-rows [w*64, w*64+64) as 4 chunks of 16; state in registers throughout.
// kt-loop: 4 tiles of 128 keys staged to LDS (K/V read from HBM exactly once
// per block); 128 MFMA per wave between barriers; 8 barriers total.
// Transposed-S (no online rescale: |s| far below f16 overflow), per-lane
// scalar row-sum, quad-reduced once at the end.
// ---------------------------------------------------------------------------
__global__ __launch_bounds__(512)
void attn_mfma(const f16* __restrict__ qb, const f16* __restrict__ kb,
               const f16* __restrict__ vb, const float* __restrict__ rel,
               f16* __restrict__ ob)
{
    __shared__ f16 Ks[128 * 64];      // [key][d-chunk8 ^ (key&7)]   16 KB
    __shared__ f16 Vt[64 * 128];      // [d][key; n-chunk8 ^ (d&7) per 64-group] 16 KB
    __shared__ f16 Pw[8][16 * 64];    // wave-private [q][key64-chunk ^ (q&7)]  16 KB
    __shared__ float relh[1024];      // rel[:,h] * log2(e)                      4 KB

    const int t = threadIdx.x;
    const int lane = t & 63, w = t >> 6;
    const int quad = lane >> 4, l16 = lane & 15;
    const int xr = l16 & 7;
    const int bh = blockIdx.x;
    const int h = bh & 15, b = bh >> 4;

    for (int i = t; i < 2 * MAXL - 1; i += 512)
        relh[i] = rel[i * NH + h] * 1.44269504f;

    // Q B-fragments (plain layout): chunk c -> Q[q=w*64+c*16+l16][d=quad*8+j (+32)]
    f16x8 qf[4][2];
    #pragma unroll
    for (int c = 0; c < 4; ++c) {
        const f16* qrow = qb + ((size_t)bh * SEQ + w * 64 + c * 16 + l16) * DH + quad * 8;
        qf[c][0] = *(const f16x8*)(qrow);
        qf[c][1] = *(const f16x8*)(qrow + 32);
    }

    f32x4 o[4][4];        // [chunk][dt]
    float lsum[4];
    #pragma unroll
    for (int c = 0; c < 4; ++c) {
        lsum[c] = 0.f;
        #pragma unroll
        for (int dt = 0; dt < 4; ++dt) o[c][dt] = f32x4{0.f, 0.f, 0.f, 0.f};
    }

    // staging sources (linear copies: global layouts already carry the swizzle)
    const f16* kbase = kb + (size_t)bh * SEQ * DH;
    const f16* vbase = vb + (size_t)bh * DH * SEQ;
    f16* pw = &Pw[w][0];

    for (int kt = 0; kt < 4; ++kt) {
        __syncthreads();
        // K tile: rows kt*128..+128, call r covers rows r*64 + w*8 + lane/8
        #pragma unroll
        for (int r = 0; r < 2; ++r) {
            const f16* src = kbase + (size_t)(kt * 128 + r * 64 + w * 8 + (lane >> 3)) * DH
                           + (lane & 7) * 8;
            gll16(src, Ks + r * 4096 + w * 512);
        }
        // V tile: Vt[d][128]; call r covers d = r*32 + w*4 + lane/16
        #pragma unroll
        for (int r = 0; r < 2; ++r) {
            const f16* src = vbase + (size_t)(r * 32 + w * 4 + (lane >> 4)) * SEQ
                           + kt * 128 + ((lane & 15) >> 3) * 64 + (lane & 7) * 8;
            gll16(src, Vt + r * 4096 + w * 512);
        }
        __syncthreads();

        #pragma unroll
        for (int c = 0; c < 4; ++c) {
            // ---- S^T = K Q^T over 128 keys (8 subtiles of 16) ----
            f32x4 sT[8];
            #pragma unroll
            for (int mt = 0; mt < 8; ++mt) {
                const f16* kr = &Ks[(mt * 16 + l16) * 64];
                f16x8 a0 = *(const f16x8*)(kr + ((quad ^ xr) * 8));
                f16x8 a1 = *(const f16x8*)(kr + (((4 + quad) ^ xr) * 8));
                f32x4 s = f32x4{0.f, 0.f, 0.f, 0.f};
                s = __builtin_amdgcn_mfma_f32_16x16x32_f16(a0, qf[c][0], s, 0, 0, 0);
                s = __builtin_amdgcn_mfma_f32_16x16x32_f16(a1, qf[c][1], s, 0, 0, 0);
                sT[mt] = s;
            }

            // ---- two 64-key halves: exp + P-relayout + PV ----
            const int cb0 = w * 64 + c * 16 + l16 + (MAXL - 1) - kt * 128 - quad * 4;
            #pragma unroll
            for (int g = 0; g < 2; ++g) {
                #pragma unroll
                for (int m4 = 0; m4 < 4; ++m4) {
                    int mt = g * 4 + m4;
                    f16x4 pk;
                    #pragma unroll
                    for (int reg = 0; reg < 4; ++reg) {
                        float e = exp2f(fmaf(sT[mt][reg], 0.180336878f,
                                             relh[cb0 - mt * 16 - reg]));
                        lsum[c] += e;
                        pk[reg] = (f16)e;
                    }
                    int c8 = (m4 * 2 + (quad >> 1)) ^ xr;
                    *(f16x4*)&pw[l16 * 64 + c8 * 8 + (quad & 1) * 4] = pk;
                }
                __builtin_amdgcn_s_waitcnt(0xC07F);   // lgkmcnt(0), wave-private P

                #pragma unroll
                for (int s2 = 0; s2 < 2; ++s2) {
                    f16x8 pa = *(const f16x8*)&pw[l16 * 64 + (((s2 * 4 + quad) ^ xr) * 8)];
                    #pragma unroll
                    for (int dt = 0; dt < 4; ++dt) {
                        const f16* vr = &Vt[(dt * 16 + l16) * 128 + g * 64];
                        f16x8 vb8 = *(const f16x8*)(vr + (((s2 * 4 + quad) ^ xr) * 8));
                        o[c][dt] = __builtin_amdgcn_mfma_f32_16x16x32_f16(
                            pa, vb8, o[c][dt], 0, 0, 0);
                    }
                }
            }
        }
    }

    // ---- finalize: quad-reduce row-sums, normalize, write f16 [b][n][h*dh] ----
    #pragma unroll
    for (int c = 0; c < 4; ++c) {
        float ls = lsum[c];
        ls += __shfl_xor(ls, 16, 64);
        ls += __shfl_xor(ls, 32, 64);
        #pragma unroll
        for (int reg = 0; reg < 4; ++reg) {
            float inv = 1.0f / __shfl(ls, quad * 4 + reg, 64);
            size_t rbase = ((size_t)b * SEQ + w * 64 + c * 16 + quad * 4 + reg) * DMODEL
                         + h * DH;
            #pragma unroll
            for (int dt = 0; dt < 4; ++dt)
                ob[rbase + dt * 16 + l16] = (f16)(o[c][dt][reg] * inv);
        }
    }
}

// ---------------------------------------------------------------------------
extern "C" void kernel_launch(void* const* d_in, const int* in_sizes, int n_in,
                              void* d_out, int out_size, void* d_ws, size_t ws_size,
                              hipStream_t stream)
{
    const float* x    = (const float*)d_in[0];
    const float* wqkv = (const float*)d_in[1];
    const float* bqkv = (const float*)d_in[2];
    const float* rel  = (const float*)d_in[3];
    const float* wout = (const float*)d_in[4];
    const float* bout = (const float*)d_in[5];
    float* out = (float*)d_out;
    char* ws = (char*)d_ws;

    const size_t XH = (size_t)MROWS * DMODEL;            // 8M elements
    f16* xh    = (f16*)(ws);
    f16* wqkvT = (f16*)(ws + 2 * XH);
    f16* woutT = wqkvT + (size_t)3 * DMODEL * DMODEL;
    f16* qbuf  = woutT + (size_t)DMODEL * DMODEL;
    f16* kbuf  = qbuf + XH;
    f16* vbuf  = kbuf + XH;
    f16* abuf  = vbuf + XH;

    prep<<<12288, 256, 0, stream>>>(x, xh, wqkv, wqkvT, wout, woutT);

    gemm_mfma<0><<<dim3(3 * DMODEL / 128, MROWS / 128), 256, 0, stream>>>(
        xh, wqkvT, bqkv, 3 * DMODEL, DMODEL, nullptr, qbuf, kbuf, vbuf);

    attn_mfma<<<NB * NH, 512, 0, stream>>>(qbuf, kbuf, vbuf, rel, abuf);

    gemm_mfma<1><<<dim3(DMODEL / 128, MROWS / 128), 256, 0, stream>>>(
        abuf, woutT, bout, DMODEL, DMODEL, out, nullptr, nullptr, nullptr);
}